// Round 2
// baseline (813.794 us; speedup 1.0000x reference)
//
#include <hip/hip_runtime.h>
#include <cmath>

#define N_TOK 8192
#define C_DIM 768
#define H_DIM 3072
#define NEXP  8
#define PADCAP 17408      // 2*N_TOK + NEXP*128
#define MAXMT  136        // PADCAP/128

typedef short short8 __attribute__((ext_vector_type(8)));
typedef float f32x4  __attribute__((ext_vector_type(4)));

// fp32 -> bf16 round-to-nearest-even (finite inputs only)
__device__ __forceinline__ unsigned short f2b(float f) {
  unsigned int u = __float_as_uint(f);
  u += 0x7fffu + ((u >> 16) & 1u);
  return (unsigned short)(u >> 16);
}

// ---------------- gating: fp64 scores, top-2, softmax, counts ----------------
__global__ __launch_bounds__(256) void gate_kernel(
    const float* __restrict__ x, const float* __restrict__ gw,
    const float* __restrict__ gb, int* __restrict__ counts,
    int* __restrict__ tok_e, int* __restrict__ tok_r, float* __restrict__ tok_w) {
  __shared__ float gwl[NEXP * C_DIM];
  __shared__ double red[256][NEXP];
  int tid = threadIdx.x;
  const float4* gw4 = (const float4*)gw;
  float4* gl4 = (float4*)gwl;
  for (int i = tid; i < NEXP * C_DIM / 4; i += 256) gl4[i] = gw4[i];
  __syncthreads();
  int tl = tid & 63;   // token within block
  int kc = tid >> 6;   // k-chunk 0..3 (192 each)
  int t = blockIdx.x * 64 + tl;
  double acc[NEXP];
#pragma unroll
  for (int e = 0; e < NEXP; e++) acc[e] = 0.0;
  const float* xr = x + (size_t)t * C_DIM;
  for (int k = kc * 192; k < kc * 192 + 192; k++) {
    double xv = (double)xr[k];
#pragma unroll
    for (int e = 0; e < NEXP; e++) acc[e] += xv * (double)gwl[e * C_DIM + k];
  }
#pragma unroll
  for (int e = 0; e < NEXP; e++) red[tid][e] = acc[e];
  __syncthreads();
  if (tid < 64) {
    double s[NEXP];
#pragma unroll
    for (int e = 0; e < NEXP; e++)
      s[e] = (double)gb[e] + red[tid][e] + red[tid + 64][e] + red[tid + 128][e] + red[tid + 192][e];
    // top-2, ties -> lower index first (matches jax.lax.top_k)
    double best = s[0], sec = -1e300; int bi = 0, si = -1;
#pragma unroll
    for (int e = 1; e < NEXP; e++) {
      if (s[e] > best)      { sec = best; si = bi; best = s[e]; bi = e; }
      else if (s[e] > sec)  { sec = s[e]; si = e; }
    }
    double ex = exp(sec - best);
    double den = 1.0 + ex;
    tok_e[2 * t] = bi;  tok_e[2 * t + 1] = si;
    tok_w[2 * t] = (float)(1.0 / den);  tok_w[2 * t + 1] = (float)(ex / den);
    tok_r[2 * t]     = atomicAdd(&counts[bi], 1);
    tok_r[2 * t + 1] = atomicAdd(&counts[si], 1);
  }
}

// ---------------- padded offsets (segments rounded up to 128 rows) ----------
__global__ void offsets_kernel(const int* __restrict__ counts, int* __restrict__ po) {
  if (threadIdx.x == 0 && blockIdx.x == 0) {
    int s = 0;
    for (int e = 0; e < NEXP; e++) { po[e] = s; s += (counts[e] + 127) & ~127; }
    po[NEXP] = s;
  }
}

// ---------------- scatter token ids + gate weights into permuted order ------
__global__ __launch_bounds__(256) void scatter_kernel(
    const int* __restrict__ tok_e, const int* __restrict__ tok_r,
    const float* __restrict__ tok_w, const int* __restrict__ po,
    int* __restrict__ perm_t, float* __restrict__ perm_w) {
  int t = blockIdx.x * 256 + threadIdx.x;
#pragma unroll
  for (int k = 0; k < 2; k++) {
    int e = tok_e[2 * t + k];
    int pos = po[e] + tok_r[2 * t + k];
    perm_t[pos] = t;
    perm_w[pos] = tok_w[2 * t + k];
  }
}

// ---------------- gather x rows into permuted bf16 matrix -------------------
__global__ __launch_bounds__(256) void gather_kernel(
    const float* __restrict__ x, const int* __restrict__ po,
    const int* __restrict__ perm_t, unsigned short* __restrict__ xg) {
  int row = blockIdx.x * 4 + (threadIdx.x >> 6);
  if (row >= po[NEXP]) return;
  int l = threadIdx.x & 63;
  int t = perm_t[row];
  const float4* src = (const float4*)(x + (size_t)t * C_DIM);
  ushort4* dst = (ushort4*)(xg + (size_t)row * C_DIM);
#pragma unroll
  for (int j = 0; j < 3; j++) {
    float4 v = src[l + j * 64];
    ushort4 o; o.x = f2b(v.x); o.y = f2b(v.y); o.z = f2b(v.z); o.w = f2b(v.w);
    dst[l + j * 64] = o;
  }
}

// ---------------- fp32 -> bf16 weight conversion ----------------------------
__global__ __launch_bounds__(256) void wconv_kernel(
    const float* __restrict__ wfc, const float* __restrict__ wproj,
    unsigned short* __restrict__ wfcb, unsigned short* __restrict__ wpjb) {
  const int n4 = NEXP * H_DIM * C_DIM / 4;
  int stride = gridDim.x * blockDim.x;
  for (int i = blockIdx.x * blockDim.x + threadIdx.x; i < 2 * n4; i += stride) {
    const float4* s; ushort4* d; int j;
    if (i < n4) { s = (const float4*)wfc;   d = (ushort4*)wfcb; j = i; }
    else        { s = (const float4*)wproj; d = (ushort4*)wpjb; j = i - n4; }
    float4 v = s[j];
    ushort4 o; o.x = f2b(v.x); o.y = f2b(v.y); o.z = f2b(v.z); o.w = f2b(v.w);
    d[j] = o;
  }
}

// ---------------- shared 128x128xK bf16 MFMA core (m97 + XOR swizzle) -------
// LDS rows are 64B (4 chunks of 16B). Chunk c of row r lives at slot
// c ^ ((r>>1)&3), which makes the 16-lane ds_read_b128 fragment read cover
// all 8 bank-groups exactly twice (2-way = free, m136) instead of 8-way.
__device__ __forceinline__ void gemm_core(
    const unsigned short* A, int lda, const unsigned short* B, int ldb, int K,
    unsigned short* lA, unsigned short* lB, int tid, f32x4 acc[4][4]) {
  int w = tid >> 6, l = tid & 63;
  int wm = (w >> 1) * 64, wn = (w & 1) * 64;
  int lrow_a = wm + (l & 15);
  int lrow_b = wn + (l & 15);
  int kc = l >> 4;                               // logical 16B chunk 0..3
  int kba = (kc ^ ((lrow_a >> 1) & 3)) * 16;     // swizzled byte offset (same for all mi)
  int kbb = (kc ^ ((lrow_b >> 1) & 3)) * 16;
  for (int k0 = 0; k0 < K; k0 += 32) {
#pragma unroll
    for (int i = 0; i < 2; i++) {
      int t2 = tid + i * 256;
      int r = t2 >> 2, pos = t2 & 3;
      int cg = pos ^ ((r >> 1) & 3);             // fetch the swizzled chunk
      const char* ga  = (const char*)(A + (size_t)r * lda + k0) + cg * 16;
      const char* gbp = (const char*)(B + (size_t)r * ldb + k0) + cg * 16;
      char* la = (char*)lA + i * 4096 + w * 1024;   // wave-uniform base + lane*16
      char* lb = (char*)lB + i * 4096 + w * 1024;
      __builtin_amdgcn_global_load_lds((const __attribute__((address_space(1))) void*)ga,
                                       (__attribute__((address_space(3))) void*)la, 16, 0, 0);
      __builtin_amdgcn_global_load_lds((const __attribute__((address_space(1))) void*)gbp,
                                       (__attribute__((address_space(3))) void*)lb, 16, 0, 0);
    }
    __syncthreads();   // drains vmcnt -> LDS tiles valid
    short8 af[4], bfr[4];
#pragma unroll
    for (int mi = 0; mi < 4; mi++)
      af[mi] = *(const short8*)((const char*)lA + (lrow_a + mi * 16) * 64 + kba);
#pragma unroll
    for (int ni = 0; ni < 4; ni++)
      bfr[ni] = *(const short8*)((const char*)lB + (lrow_b + ni * 16) * 64 + kbb);
#pragma unroll
    for (int mi = 0; mi < 4; mi++) {
#pragma unroll
      for (int ni = 0; ni < 4; ni++)
        acc[mi][ni] = __builtin_amdgcn_mfma_f32_16x16x32_bf16(af[mi], bfr[ni], acc[mi][ni], 0, 0, 0);
    }
    __syncthreads();   // all waves done reading before next overwrite
  }
}

// ---------------- FC1: h = gelu(xg @ w_fc^T + b_fc), bf16 out ---------------
// 1-D grid 3264 = 8 XCD-slots x 17 strips x 24 col-blocks. bid%8 pins all 24
// col-blocks of one A-strip to one XCD, temporally adjacent -> A strip read
// once into that XCD's L2.
__global__ __launch_bounds__(256) void fc1_kernel(
    const unsigned short* __restrict__ xg, const unsigned short* __restrict__ wfcb,
    const float* __restrict__ bfc, const int* __restrict__ po,
    unsigned short* __restrict__ h) {
  __shared__ unsigned short lA[128 * 32];
  __shared__ unsigned short lB[128 * 32];
  int bid = blockIdx.x;
  int r8 = bid & 7, g8 = bid >> 3;     // g8: 0..407
  int col = g8 % 24;
  int Sp  = g8 / 24;                   // 0..16
  int y   = r8 * 17 + Sp;              // 0..135
  int row0 = y * 128;
  if (row0 >= po[NEXP]) return;
  int e = 0;
#pragma unroll
  for (int i = 1; i < NEXP; i++) if (row0 >= po[i]) e = i;
  int n0 = col * 128;
  int tid = threadIdx.x;
  f32x4 acc[4][4];
#pragma unroll
  for (int mi = 0; mi < 4; mi++)
#pragma unroll
    for (int ni = 0; ni < 4; ni++) acc[mi][ni] = (f32x4){0.f, 0.f, 0.f, 0.f};
  gemm_core(xg + (size_t)row0 * C_DIM, C_DIM,
            wfcb + (size_t)e * H_DIM * C_DIM + (size_t)n0 * C_DIM, C_DIM, C_DIM,
            lA, lB, tid, acc);
  int w = tid >> 6, l = tid & 63;
  int wm = (w >> 1) * 64, wn = (w & 1) * 64;
  const float* bias = bfc + (size_t)e * H_DIM;
#pragma unroll
  for (int ni = 0; ni < 4; ni++) {
    int colw = n0 + wn + ni * 16 + (l & 15);
    float bv = bias[colw];
#pragma unroll
    for (int mi = 0; mi < 4; mi++) {
#pragma unroll
      for (int r = 0; r < 4; r++) {
        int row = row0 + wm + mi * 16 + (l >> 4) * 4 + r;
        float v = acc[mi][ni][r] + bv;
        float g = 0.5f * v * (1.0f + tanhf(0.7978845608028654f * (v + 0.044715f * v * v * v)));
        h[(size_t)row * H_DIM + colw] = f2b(g);
      }
    }
  }
}

// ---------------- FC2: out[token] += w * (h @ w_proj^T + b_proj) ------------
// split-K=4 (768 each) for occupancy: 3264 blocks. 1-D grid, XCD swizzle:
// bid%8 pins the 6 col-blocks of one (strip, ksplit) to one XCD.
__global__ __launch_bounds__(256) void fc2_kernel(
    const unsigned short* __restrict__ h, const unsigned short* __restrict__ wpjb,
    const float* __restrict__ bproj, const int* __restrict__ po,
    const int* __restrict__ perm_t, const float* __restrict__ perm_w,
    float* __restrict__ out) {
  __shared__ unsigned short lA[128 * 32];
  __shared__ unsigned short lB[128 * 32];
  int bid = blockIdx.x;
  int r8 = bid & 7, g8 = bid >> 3;     // g8: 0..407
  int col = g8 % 6;
  int Sp  = g8 / 6;                    // 0..67
  int S   = r8 * 68 + Sp;             // 0..543 = z*136 + y
  int z   = S / 136;                   // k-split 0..3
  int y   = S - z * 136;
  int row0 = y * 128;
  if (row0 >= po[NEXP]) return;
  int e = 0;
#pragma unroll
  for (int i = 1; i < NEXP; i++) if (row0 >= po[i]) e = i;
  int n0 = col * 128;
  int koff = z * (H_DIM / 4);
  int tid = threadIdx.x;
  f32x4 acc[4][4];
#pragma unroll
  for (int mi = 0; mi < 4; mi++)
#pragma unroll
    for (int ni = 0; ni < 4; ni++) acc[mi][ni] = (f32x4){0.f, 0.f, 0.f, 0.f};
  gemm_core(h + (size_t)row0 * H_DIM + koff, H_DIM,
            wpjb + (size_t)e * C_DIM * H_DIM + (size_t)n0 * H_DIM + koff, H_DIM, H_DIM / 4,
            lA, lB, tid, acc);
  int w = tid >> 6, l = tid & 63;
  int wm = (w >> 1) * 64, wn = (w & 1) * 64;
  const float* bias = bproj + (size_t)e * C_DIM;
#pragma unroll
  for (int mi = 0; mi < 4; mi++) {
#pragma unroll
    for (int r = 0; r < 4; r++) {
      int pos = row0 + wm + mi * 16 + (l >> 4) * 4 + r;
      int tk = perm_t[pos];
      float wgt = perm_w[pos];
      if (wgt != 0.f) {
#pragma unroll
        for (int ni = 0; ni < 4; ni++) {
          int colw = n0 + wn + ni * 16 + (l & 15);
          float v = acc[mi][ni][r];
          if (z == 0) v += bias[colw];        // bias exactly once across splits
          atomicAdd(&out[(size_t)tk * C_DIM + colw], v * wgt);
        }
      }
    }
  }
}

extern "C" void kernel_launch(void* const* d_in, const int* in_sizes, int n_in,
                              void* d_out, int out_size, void* d_ws, size_t ws_size,
                              hipStream_t stream) {
  const float* x     = (const float*)d_in[0];
  const float* gw    = (const float*)d_in[1];
  const float* gb    = (const float*)d_in[2];
  const float* wfc   = (const float*)d_in[3];
  const float* bfc   = (const float*)d_in[4];
  const float* wproj = (const float*)d_in[5];
  const float* bproj = (const float*)d_in[6];
  float* out = (float*)d_out;
  char* ws = (char*)d_ws;

  // ws layout (total ~210 MB)
  int*   counts = (int*)(ws + 0);
  int*   po     = (int*)(ws + 64);
  int*   tok_e  = (int*)(ws + 256);
  int*   tok_r  = (int*)(ws + 256 + 65536);
  float* tok_w  = (float*)(ws + 256 + 131072);
  int*   perm_t = (int*)(ws + 256 + 196608);
  float* perm_w = (float*)(ws + 256 + 196608 + 69632);
  const size_t ROUT_END = 336128;
  unsigned short* xg   = (unsigned short*)(ws + ROUT_END);      // 17408x768 bf16
  unsigned short* wfcb = (unsigned short*)(ws + 27074816);      // 8x3072x768 bf16
  unsigned short* wpjb = (unsigned short*)(ws + 64823552);      // 8x768x3072 bf16
  unsigned short* hbuf = (unsigned short*)(ws + 102572288);     // 17408x3072 bf16

  hipMemsetAsync(ws, 0, ROUT_END, stream);
  hipMemsetAsync(d_out, 0, (size_t)N_TOK * C_DIM * sizeof(float), stream);

  gate_kernel<<<N_TOK / 64, 256, 0, stream>>>(x, gw, gb, counts, tok_e, tok_r, tok_w);
  offsets_kernel<<<1, 64, 0, stream>>>(counts, po);
  scatter_kernel<<<N_TOK / 256, 256, 0, stream>>>(tok_e, tok_r, tok_w, po, perm_t, perm_w);
  gather_kernel<<<PADCAP / 4, 256, 0, stream>>>(x, po, perm_t, xg);
  wconv_kernel<<<2048, 256, 0, stream>>>(wfc, wproj, wfcb, wpjb);
  fc1_kernel<<<8 * 17 * 24, 256, 0, stream>>>(xg, wfcb, bfc, po, hbuf);
  fc2_kernel<<<8 * 68 * 6, 256, 0, stream>>>(hbuf, wpjb, bproj, po, perm_t, perm_w, out);
}

// Round 3
// 619.901 us; speedup vs baseline: 1.3128x; 1.3128x over previous
//
#include <hip/hip_runtime.h>
#include <cmath>

#define N_TOK 8192
#define C_DIM 768
#define H_DIM 3072
#define NEXP  8
#define PADCAP 17408      // 2*N_TOK + NEXP*128
#define MAXMT  136        // PADCAP/128

typedef short short8 __attribute__((ext_vector_type(8)));
typedef float f32x4  __attribute__((ext_vector_type(4)));

// fp32 -> bf16 round-to-nearest-even (finite inputs only)
__device__ __forceinline__ unsigned short f2b(float f) {
  unsigned int u = __float_as_uint(f);
  u += 0x7fffu + ((u >> 16) & 1u);
  return (unsigned short)(u >> 16);
}
__device__ __forceinline__ float b2f(unsigned short u) {
  return __uint_as_float((unsigned int)u << 16);
}

// ---------------- gating: fp64 scores, top-2, softmax, counts ----------------
__global__ __launch_bounds__(256) void gate_kernel(
    const float* __restrict__ x, const float* __restrict__ gw,
    const float* __restrict__ gb, int* __restrict__ counts,
    int* __restrict__ tok_e, int* __restrict__ tok_r, float* __restrict__ tok_w) {
  __shared__ float gwl[NEXP * C_DIM];
  __shared__ double red[256][NEXP];
  int tid = threadIdx.x;
  const float4* gw4 = (const float4*)gw;
  float4* gl4 = (float4*)gwl;
  for (int i = tid; i < NEXP * C_DIM / 4; i += 256) gl4[i] = gw4[i];
  __syncthreads();
  int tl = tid & 63;   // token within block
  int kc = tid >> 6;   // k-chunk 0..3 (192 each)
  int t = blockIdx.x * 64 + tl;
  double acc[NEXP];
#pragma unroll
  for (int e = 0; e < NEXP; e++) acc[e] = 0.0;
  const float* xr = x + (size_t)t * C_DIM;
  for (int k = kc * 192; k < kc * 192 + 192; k++) {
    double xv = (double)xr[k];
#pragma unroll
    for (int e = 0; e < NEXP; e++) acc[e] += xv * (double)gwl[e * C_DIM + k];
  }
#pragma unroll
  for (int e = 0; e < NEXP; e++) red[tid][e] = acc[e];
  __syncthreads();
  if (tid < 64) {
    double s[NEXP];
#pragma unroll
    for (int e = 0; e < NEXP; e++)
      s[e] = (double)gb[e] + red[tid][e] + red[tid + 64][e] + red[tid + 128][e] + red[tid + 192][e];
    // top-2, ties -> lower index first (matches jax.lax.top_k)
    double best = s[0], sec = -1e300; int bi = 0, si = -1;
#pragma unroll
    for (int e = 1; e < NEXP; e++) {
      if (s[e] > best)      { sec = best; si = bi; best = s[e]; bi = e; }
      else if (s[e] > sec)  { sec = s[e]; si = e; }
    }
    double ex = exp(sec - best);
    double den = 1.0 + ex;
    tok_e[2 * t] = bi;  tok_e[2 * t + 1] = si;
    tok_w[2 * t] = (float)(1.0 / den);  tok_w[2 * t + 1] = (float)(ex / den);
    tok_r[2 * t]     = atomicAdd(&counts[bi], 1);
    tok_r[2 * t + 1] = atomicAdd(&counts[si], 1);
  }
}

// ---------------- padded offsets (segments rounded up to 128 rows) ----------
__global__ void offsets_kernel(const int* __restrict__ counts, int* __restrict__ po) {
  if (threadIdx.x == 0 && blockIdx.x == 0) {
    int s = 0;
    for (int e = 0; e < NEXP; e++) { po[e] = s; s += (counts[e] + 127) & ~127; }
    po[NEXP] = s;
  }
}

// -------- scatter token ids + gate weights; record inverse map tok_pos ------
__global__ __launch_bounds__(256) void scatter_kernel(
    const int* __restrict__ tok_e, const int* __restrict__ tok_r,
    const float* __restrict__ tok_w, const int* __restrict__ po,
    int* __restrict__ perm_t, float* __restrict__ perm_w,
    int* __restrict__ tok_pos) {
  int t = blockIdx.x * 256 + threadIdx.x;
#pragma unroll
  for (int k = 0; k < 2; k++) {
    int e = tok_e[2 * t + k];
    int pos = po[e] + tok_r[2 * t + k];
    perm_t[pos] = t;
    perm_w[pos] = tok_w[2 * t + k];
    tok_pos[2 * t + k] = pos;
  }
}

// ---------------- gather x rows into permuted bf16 matrix -------------------
__global__ __launch_bounds__(256) void gather_kernel(
    const float* __restrict__ x, const int* __restrict__ po,
    const int* __restrict__ perm_t, unsigned short* __restrict__ xg) {
  int row = blockIdx.x * 4 + (threadIdx.x >> 6);
  if (row >= po[NEXP]) return;
  int l = threadIdx.x & 63;
  int t = perm_t[row];
  const float4* src = (const float4*)(x + (size_t)t * C_DIM);
  ushort4* dst = (ushort4*)(xg + (size_t)row * C_DIM);
#pragma unroll
  for (int j = 0; j < 3; j++) {
    float4 v = src[l + j * 64];
    ushort4 o; o.x = f2b(v.x); o.y = f2b(v.y); o.z = f2b(v.z); o.w = f2b(v.w);
    dst[l + j * 64] = o;
  }
}

// ---------------- fp32 -> bf16 weight conversion ----------------------------
__global__ __launch_bounds__(256) void wconv_kernel(
    const float* __restrict__ wfc, const float* __restrict__ wproj,
    unsigned short* __restrict__ wfcb, unsigned short* __restrict__ wpjb) {
  const int n4 = NEXP * H_DIM * C_DIM / 4;
  int stride = gridDim.x * blockDim.x;
  for (int i = blockIdx.x * blockDim.x + threadIdx.x; i < 2 * n4; i += stride) {
    const float4* s; ushort4* d; int j;
    if (i < n4) { s = (const float4*)wfc;   d = (ushort4*)wfcb; j = i; }
    else        { s = (const float4*)wproj; d = (ushort4*)wpjb; j = i - n4; }
    float4 v = s[j];
    ushort4 o; o.x = f2b(v.x); o.y = f2b(v.y); o.z = f2b(v.z); o.w = f2b(v.w);
    d[j] = o;
  }
}

// ---------------- shared 128x128xK bf16 MFMA core (m97 + XOR swizzle) -------
// LDS rows are 64B (4 chunks of 16B). Chunk c of row r lives at slot
// c ^ ((r>>1)&3): the 16-lane ds_read_b128 fragment read covers all 8
// bank-groups exactly twice (2-way = free, m136). Verified R2: conflicts = 0.
__device__ __forceinline__ void gemm_core(
    const unsigned short* A, int lda, const unsigned short* B, int ldb, int K,
    unsigned short* lA, unsigned short* lB, int tid, f32x4 acc[4][4]) {
  int w = tid >> 6, l = tid & 63;
  int wm = (w >> 1) * 64, wn = (w & 1) * 64;
  int lrow_a = wm + (l & 15);
  int lrow_b = wn + (l & 15);
  int kc = l >> 4;                               // logical 16B chunk 0..3
  int kba = (kc ^ ((lrow_a >> 1) & 3)) * 16;     // swizzled byte offset
  int kbb = (kc ^ ((lrow_b >> 1) & 3)) * 16;
  for (int k0 = 0; k0 < K; k0 += 32) {
#pragma unroll
    for (int i = 0; i < 2; i++) {
      int t2 = tid + i * 256;
      int r = t2 >> 2, pos = t2 & 3;
      int cg = pos ^ ((r >> 1) & 3);             // fetch the swizzled chunk
      const char* ga  = (const char*)(A + (size_t)r * lda + k0) + cg * 16;
      const char* gbp = (const char*)(B + (size_t)r * ldb + k0) + cg * 16;
      char* la = (char*)lA + i * 4096 + w * 1024;   // wave-uniform base + lane*16
      char* lb = (char*)lB + i * 4096 + w * 1024;
      __builtin_amdgcn_global_load_lds((const __attribute__((address_space(1))) void*)ga,
                                       (__attribute__((address_space(3))) void*)la, 16, 0, 0);
      __builtin_amdgcn_global_load_lds((const __attribute__((address_space(1))) void*)gbp,
                                       (__attribute__((address_space(3))) void*)lb, 16, 0, 0);
    }
    __syncthreads();   // drains vmcnt -> LDS tiles valid
    short8 af[4], bfr[4];
#pragma unroll
    for (int mi = 0; mi < 4; mi++)
      af[mi] = *(const short8*)((const char*)lA + (lrow_a + mi * 16) * 64 + kba);
#pragma unroll
    for (int ni = 0; ni < 4; ni++)
      bfr[ni] = *(const short8*)((const char*)lB + (lrow_b + ni * 16) * 64 + kbb);
#pragma unroll
    for (int mi = 0; mi < 4; mi++) {
#pragma unroll
      for (int ni = 0; ni < 4; ni++)
        acc[mi][ni] = __builtin_amdgcn_mfma_f32_16x16x32_bf16(af[mi], bfr[ni], acc[mi][ni], 0, 0, 0);
    }
    __syncthreads();   // all waves done reading before next overwrite
  }
}

// ---------------- FC1: h = gelu(xg @ w_fc^T + b_fc), bf16 out ---------------
// 1-D grid 3264 = 8 XCD-slots x 17 strips x 24 col-blocks. bid%8 pins all 24
// col-blocks of one A-strip to one XCD (R2: FETCH dropped 5x -> keep).
__global__ __launch_bounds__(256) void fc1_kernel(
    const unsigned short* __restrict__ xg, const unsigned short* __restrict__ wfcb,
    const float* __restrict__ bfc, const int* __restrict__ po,
    unsigned short* __restrict__ h) {
  __shared__ unsigned short lA[128 * 32];
  __shared__ unsigned short lB[128 * 32];
  int bid = blockIdx.x;
  int r8 = bid & 7, g8 = bid >> 3;     // g8: 0..407
  int col = g8 % 24;
  int Sp  = g8 / 24;                   // 0..16
  int y   = r8 * 17 + Sp;              // 0..135
  int row0 = y * 128;
  if (row0 >= po[NEXP]) return;
  int e = 0;
#pragma unroll
  for (int i = 1; i < NEXP; i++) if (row0 >= po[i]) e = i;
  int n0 = col * 128;
  int tid = threadIdx.x;
  f32x4 acc[4][4];
#pragma unroll
  for (int mi = 0; mi < 4; mi++)
#pragma unroll
    for (int ni = 0; ni < 4; ni++) acc[mi][ni] = (f32x4){0.f, 0.f, 0.f, 0.f};
  gemm_core(xg + (size_t)row0 * C_DIM, C_DIM,
            wfcb + (size_t)e * H_DIM * C_DIM + (size_t)n0 * C_DIM, C_DIM, C_DIM,
            lA, lB, tid, acc);
  int w = tid >> 6, l = tid & 63;
  int wm = (w >> 1) * 64, wn = (w & 1) * 64;
  const float* bias = bfc + (size_t)e * H_DIM;
#pragma unroll
  for (int ni = 0; ni < 4; ni++) {
    int colw = n0 + wn + ni * 16 + (l & 15);
    float bv = bias[colw];
#pragma unroll
    for (int mi = 0; mi < 4; mi++) {
#pragma unroll
      for (int r = 0; r < 4; r++) {
        int row = row0 + wm + mi * 16 + (l >> 4) * 4 + r;
        float v = acc[mi][ni][r] + bv;
        float g = 0.5f * v * (1.0f + tanhf(0.7978845608028654f * (v + 0.044715f * v * v * v)));
        h[(size_t)row * H_DIM + colw] = f2b(g);
      }
    }
  }
}

// ---------------- FC2: part[z][pos] = w * (h_z @ w_proj^T + b_proj*[z==0]) --
// split-K=2 (K=1536 each), 1632 blocks, NO atomics: weighted bf16 partials
// with plain stores; combine_kernel does the deterministic 4-way sum.
__global__ __launch_bounds__(256) void fc2_kernel(
    const unsigned short* __restrict__ h, const unsigned short* __restrict__ wpjb,
    const float* __restrict__ bproj, const int* __restrict__ po,
    const float* __restrict__ perm_w, unsigned short* __restrict__ part) {
  __shared__ unsigned short lA[128 * 32];
  __shared__ unsigned short lB[128 * 32];
  int bid = blockIdx.x;
  int r8 = bid & 7, g8 = bid >> 3;     // g8: 0..203
  int col = g8 % 6;
  int Sp  = g8 / 6;                    // 0..33
  int S   = r8 * 34 + Sp;              // 0..271 = z*136 + y
  int z   = S / 136;                   // k-split 0..1
  int y   = S - z * 136;
  int row0 = y * 128;
  if (row0 >= po[NEXP]) return;
  int e = 0;
#pragma unroll
  for (int i = 1; i < NEXP; i++) if (row0 >= po[i]) e = i;
  int n0 = col * 128;
  int koff = z * (H_DIM / 2);
  int tid = threadIdx.x;
  f32x4 acc[4][4];
#pragma unroll
  for (int mi = 0; mi < 4; mi++)
#pragma unroll
    for (int ni = 0; ni < 4; ni++) acc[mi][ni] = (f32x4){0.f, 0.f, 0.f, 0.f};
  gemm_core(h + (size_t)row0 * H_DIM + koff, H_DIM,
            wpjb + (size_t)e * C_DIM * H_DIM + (size_t)n0 * H_DIM + koff, H_DIM, H_DIM / 2,
            lA, lB, tid, acc);
  int w = tid >> 6, l = tid & 63;
  int wm = (w >> 1) * 64, wn = (w & 1) * 64;
  const float* bias = bproj + (size_t)e * C_DIM;
  unsigned short* pz = part + (size_t)z * PADCAP * C_DIM;
#pragma unroll
  for (int mi = 0; mi < 4; mi++) {
#pragma unroll
    for (int r = 0; r < 4; r++) {
      int pos = row0 + wm + mi * 16 + (l >> 4) * 4 + r;
      float wgt = perm_w[pos];   // 0 for pad rows -> stores 0, never read
#pragma unroll
      for (int ni = 0; ni < 4; ni++) {
        int colw = n0 + wn + ni * 16 + (l & 15);
        float v = acc[mi][ni][r];
        if (z == 0) v += bias[colw];        // bias exactly once across splits
        pz[(size_t)pos * C_DIM + colw] = f2b(v * wgt);
      }
    }
  }
}

// ---------------- combine: out[t] = sum of the token's 4 partial rows -------
__global__ __launch_bounds__(256) void combine_kernel(
    const unsigned short* __restrict__ part, const int* __restrict__ tok_pos,
    float* __restrict__ out) {
  const int NC4 = C_DIM / 4;                       // 192
  int idx = blockIdx.x * 256 + threadIdx.x;        // 0 .. N_TOK*192-1
  int t = idx / NC4, c4 = idx - t * NC4;
  int p0 = tok_pos[2 * t], p1 = tok_pos[2 * t + 1];
  const size_t SP = (size_t)PADCAP * C_DIM;
  const unsigned short* r00 = part + (size_t)p0 * C_DIM + c4 * 4;
  const unsigned short* r10 = part + (size_t)p1 * C_DIM + c4 * 4;
  ushort4 v00 = *(const ushort4*)r00;
  ushort4 v01 = *(const ushort4*)(r00 + SP);
  ushort4 v10 = *(const ushort4*)r10;
  ushort4 v11 = *(const ushort4*)(r10 + SP);
  float4 o;
  o.x = b2f(v00.x) + b2f(v01.x) + b2f(v10.x) + b2f(v11.x);
  o.y = b2f(v00.y) + b2f(v01.y) + b2f(v10.y) + b2f(v11.y);
  o.z = b2f(v00.z) + b2f(v01.z) + b2f(v10.z) + b2f(v11.z);
  o.w = b2f(v00.w) + b2f(v01.w) + b2f(v10.w) + b2f(v11.w);
  ((float4*)out)[idx] = o;
}

extern "C" void kernel_launch(void* const* d_in, const int* in_sizes, int n_in,
                              void* d_out, int out_size, void* d_ws, size_t ws_size,
                              hipStream_t stream) {
  const float* x     = (const float*)d_in[0];
  const float* gw    = (const float*)d_in[1];
  const float* gb    = (const float*)d_in[2];
  const float* wfc   = (const float*)d_in[3];
  const float* bfc   = (const float*)d_in[4];
  const float* wproj = (const float*)d_in[5];
  const float* bproj = (const float*)d_in[6];
  float* out = (float*)d_out;
  char* ws = (char*)d_ws;

  // ws layout (~209.6 MB total; part overlays xg+wfcb which die after FC1)
  int*   counts  = (int*)(ws + 0);
  int*   po      = (int*)(ws + 64);
  int*   tok_e   = (int*)(ws + 256);
  int*   tok_r   = (int*)(ws + 65792);
  float* tok_w   = (float*)(ws + 131328);
  int*   tok_pos = (int*)(ws + 196864);
  int*   perm_t  = (int*)(ws + 262400);
  float* perm_w  = (float*)(ws + 332032);
  const size_t ROUT_END = 401920;
  unsigned short* wpjb = (unsigned short*)(ws + 401920);        // 8x768x3072 bf16 -> ends 38,150,656
  unsigned short* hbuf = (unsigned short*)(ws + 38150656);      // 17408x3072 bf16 -> ends 145,105,408
  unsigned short* xg   = (unsigned short*)(ws + 145105408);     // 17408x768 bf16  -> ends 171,844,096
  unsigned short* wfcb = (unsigned short*)(ws + 171844096);     // 8x3072x768 bf16 -> ends 209,592,832
  unsigned short* part = (unsigned short*)(ws + 145105408);     // 2x17408x768 bf16 (overlay, ends 198,582,784)

  hipMemsetAsync(ws, 0, ROUT_END, stream);

  gate_kernel<<<N_TOK / 64, 256, 0, stream>>>(x, gw, gb, counts, tok_e, tok_r, tok_w);
  offsets_kernel<<<1, 64, 0, stream>>>(counts, po);
  scatter_kernel<<<N_TOK / 256, 256, 0, stream>>>(tok_e, tok_r, tok_w, po, perm_t, perm_w, tok_pos);
  gather_kernel<<<PADCAP / 4, 256, 0, stream>>>(x, po, perm_t, xg);
  wconv_kernel<<<2048, 256, 0, stream>>>(wfc, wproj, wfcb, wpjb);
  fc1_kernel<<<8 * 17 * 24, 256, 0, stream>>>(xg, wfcb, bfc, po, hbuf);
  fc2_kernel<<<8 * 34 * 6, 256, 0, stream>>>(hbuf, wpjb, bproj, po, perm_w, part);
  combine_kernel<<<N_TOK * (C_DIM / 4) / 256, 256, 0, stream>>>(part, tok_pos, out);
}

// Round 4
// 531.890 us; speedup vs baseline: 1.5300x; 1.1655x over previous
//
#include <hip/hip_runtime.h>
#include <cmath>

#define N_TOK 8192
#define C_DIM 768
#define H_DIM 3072
#define NEXP  8
#define PADCAP 17408      // 2*N_TOK + NEXP*128
#define MAXMT  136        // PADCAP/128

typedef short short8 __attribute__((ext_vector_type(8)));
typedef float f32x4  __attribute__((ext_vector_type(4)));

// fp32 -> bf16 round-to-nearest-even (finite inputs only)
__device__ __forceinline__ unsigned short f2b(float f) {
  unsigned int u = __float_as_uint(f);
  u += 0x7fffu + ((u >> 16) & 1u);
  return (unsigned short)(u >> 16);
}
__device__ __forceinline__ float b2f(unsigned short u) {
  return __uint_as_float((unsigned int)u << 16);
}
__device__ __forceinline__ void gll(const char* g, char* l) {
  __builtin_amdgcn_global_load_lds((const __attribute__((address_space(1))) void*)g,
                                   (__attribute__((address_space(3))) void*)l, 16, 0, 0);
}

// ---------------- gating: fp64 scores, top-2, softmax, counts ----------------
__global__ __launch_bounds__(256) void gate_kernel(
    const float* __restrict__ x, const float* __restrict__ gw,
    const float* __restrict__ gb, int* __restrict__ counts,
    int* __restrict__ tok_e, int* __restrict__ tok_r, float* __restrict__ tok_w) {
  __shared__ float gwl[NEXP * C_DIM];
  __shared__ double red[256][NEXP];
  int tid = threadIdx.x;
  const float4* gw4 = (const float4*)gw;
  float4* gl4 = (float4*)gwl;
  for (int i = tid; i < NEXP * C_DIM / 4; i += 256) gl4[i] = gw4[i];
  __syncthreads();
  int tl = tid & 63;   // token within block
  int kc = tid >> 6;   // k-chunk 0..3 (192 each)
  int t = blockIdx.x * 64 + tl;
  double acc[NEXP];
#pragma unroll
  for (int e = 0; e < NEXP; e++) acc[e] = 0.0;
  const float* xr = x + (size_t)t * C_DIM;
  for (int k = kc * 192; k < kc * 192 + 192; k++) {
    double xv = (double)xr[k];
#pragma unroll
    for (int e = 0; e < NEXP; e++) acc[e] += xv * (double)gwl[e * C_DIM + k];
  }
#pragma unroll
  for (int e = 0; e < NEXP; e++) red[tid][e] = acc[e];
  __syncthreads();
  if (tid < 64) {
    double s[NEXP];
#pragma unroll
    for (int e = 0; e < NEXP; e++)
      s[e] = (double)gb[e] + red[tid][e] + red[tid + 64][e] + red[tid + 128][e] + red[tid + 192][e];
    // top-2, ties -> lower index first (matches jax.lax.top_k)
    double best = s[0], sec = -1e300; int bi = 0, si = -1;
#pragma unroll
    for (int e = 1; e < NEXP; e++) {
      if (s[e] > best)      { sec = best; si = bi; best = s[e]; bi = e; }
      else if (s[e] > sec)  { sec = s[e]; si = e; }
    }
    double ex = exp(sec - best);
    double den = 1.0 + ex;
    tok_e[2 * t] = bi;  tok_e[2 * t + 1] = si;
    tok_w[2 * t] = (float)(1.0 / den);  tok_w[2 * t + 1] = (float)(ex / den);
    tok_r[2 * t]     = atomicAdd(&counts[bi], 1);
    tok_r[2 * t + 1] = atomicAdd(&counts[si], 1);
  }
}

// ---------------- padded offsets (segments rounded up to 128 rows) ----------
__global__ void offsets_kernel(const int* __restrict__ counts, int* __restrict__ po) {
  if (threadIdx.x == 0 && blockIdx.x == 0) {
    int s = 0;
    for (int e = 0; e < NEXP; e++) { po[e] = s; s += (counts[e] + 127) & ~127; }
    po[NEXP] = s;
  }
}

// -------- scatter token ids + gate weights; record inverse map tok_pos ------
__global__ __launch_bounds__(256) void scatter_kernel(
    const int* __restrict__ tok_e, const int* __restrict__ tok_r,
    const float* __restrict__ tok_w, const int* __restrict__ po,
    int* __restrict__ perm_t, float* __restrict__ perm_w,
    int* __restrict__ tok_pos) {
  int t = blockIdx.x * 256 + threadIdx.x;
#pragma unroll
  for (int k = 0; k < 2; k++) {
    int e = tok_e[2 * t + k];
    int pos = po[e] + tok_r[2 * t + k];
    perm_t[pos] = t;
    perm_w[pos] = tok_w[2 * t + k];
    tok_pos[2 * t + k] = pos;
  }
}

// ---------------- gather x rows into permuted bf16 matrix -------------------
__global__ __launch_bounds__(256) void gather_kernel(
    const float* __restrict__ x, const int* __restrict__ po,
    const int* __restrict__ perm_t, unsigned short* __restrict__ xg) {
  int row = blockIdx.x * 4 + (threadIdx.x >> 6);
  if (row >= po[NEXP]) return;
  int l = threadIdx.x & 63;
  int t = perm_t[row];
  const float4* src = (const float4*)(x + (size_t)t * C_DIM);
  ushort4* dst = (ushort4*)(xg + (size_t)row * C_DIM);
#pragma unroll
  for (int j = 0; j < 3; j++) {
    float4 v = src[l + j * 64];
    ushort4 o; o.x = f2b(v.x); o.y = f2b(v.y); o.z = f2b(v.z); o.w = f2b(v.w);
    dst[l + j * 64] = o;
  }
}

// ---------------- fp32 -> bf16 weight conversion ----------------------------
__global__ __launch_bounds__(256) void wconv_kernel(
    const float* __restrict__ wfc, const float* __restrict__ wproj,
    unsigned short* __restrict__ wfcb, unsigned short* __restrict__ wpjb) {
  const int n4 = NEXP * H_DIM * C_DIM / 4;
  int stride = gridDim.x * blockDim.x;
  for (int i = blockIdx.x * blockDim.x + threadIdx.x; i < 2 * n4; i += stride) {
    const float4* s; ushort4* d; int j;
    if (i < n4) { s = (const float4*)wfc;   d = (ushort4*)wfcb; j = i; }
    else        { s = (const float4*)wproj; d = (ushort4*)wpjb; j = i - n4; }
    float4 v = s[j];
    ushort4 o; o.x = f2b(v.x); o.y = f2b(v.y); o.z = f2b(v.z); o.w = f2b(v.w);
    d[j] = o;
  }
}

// ---------- 512-thread 128x128 tile, BK=64, LDS double-buffer ----------
// 8 waves in 2x4: wave tile 64x32 -> acc 4x2 f32x4 = 32 AGPR (keeps
// VGPR+AGPR <= 128 -> 4 waves/SIMD, 2 blocks/CU). One barrier per K-iter;
// prefetch for iter k+1 issued before compute of iter k, so the vmcnt(0)
// drain at the next barrier waits on loads aged by a full compute phase.
// LDS rows are 128B (8 chunks of 16B); chunk c of row r at slot c^((r>>1)&7)
// -> 16-lane ds_read_b128 group covers all 8 bank-groups 2x (free, m136).
// lds layout: buf(0/1)*32768 | A tile 16KB | B tile 16KB
__device__ __forceinline__ void gemm_core512(
    const unsigned short* A, int lda, const unsigned short* B, int ldb, int K,
    char* lds, int tid, f32x4 acc[4][2]) {
  const int w = tid >> 6, l = tid & 63;
  const int wr = w >> 2, wc = w & 3;
  const int rowa = wr * 64 + (l & 15);
  const int rowb = wc * 32 + (l & 15);
  const int kc = l >> 4;
  const int sa0 = (kc ^ ((rowa >> 1) & 7)) * 16;
  const int sb0 = (kc ^ ((rowb >> 1) & 7)) * 16;
  // staging: 2048 chunks of 16B (1024 A + 1024 B); thread handles A chunks
  // {tid, 512+tid} and B chunks {tid, 512+tid}. LDS dest = region + cid*16.
  const int r0 = tid >> 3,          cg0 = (tid & 7) ^ ((r0 >> 1) & 7);
  const int r1 = (512 + tid) >> 3,  cg1 = ((512 + tid) & 7) ^ ((r1 >> 1) & 7);
  const char* gA0 = (const char*)(A + (size_t)r0 * lda) + cg0 * 16;
  const char* gA1 = (const char*)(A + (size_t)r1 * lda) + cg1 * 16;
  const char* gB0 = (const char*)(B + (size_t)r0 * ldb) + cg0 * 16;
  const char* gB1 = (const char*)(B + (size_t)r1 * ldb) + cg1 * 16;
  const int wb = w * 1024;           // wave-uniform LDS base (+ lane*16 by HW)
  const int iters = K >> 6;
  // prologue: tile 0 -> buf 0
  gll(gA0, lds + wb);
  gll(gA1, lds + 8192 + wb);
  gll(gB0, lds + 16384 + wb);
  gll(gB1, lds + 24576 + wb);
#pragma unroll 1
  for (int kt = 0; kt < iters; kt++) {
    __syncthreads();                       // publishes buf kt&1
    if (kt + 1 < iters) {                  // prefetch tile kt+1 -> other buf
      size_t kb = (size_t)(kt + 1) * 128;  // 64 elems * 2B
      char* nb = lds + ((kt + 1) & 1) * 32768;
      gll(gA0 + kb, nb + wb);
      gll(gA1 + kb, nb + 8192 + wb);
      gll(gB0 + kb, nb + 16384 + wb);
      gll(gB1 + kb, nb + 24576 + wb);
    }
    char* bb = lds + (kt & 1) * 32768;
#pragma unroll
    for (int s = 0; s < 2; s++) {
      const int sxa = sa0 ^ (s << 6);      // chunk index ^4 == byte ^64
      const int sxb = sb0 ^ (s << 6);
      short8 af[4], bf2[2];
#pragma unroll
      for (int mi = 0; mi < 4; mi++)
        af[mi] = *(const short8*)(bb + (rowa + mi * 16) * 128 + sxa);
#pragma unroll
      for (int ni = 0; ni < 2; ni++)
        bf2[ni] = *(const short8*)(bb + 16384 + (rowb + ni * 16) * 128 + sxb);
#pragma unroll
      for (int mi = 0; mi < 4; mi++)
#pragma unroll
        for (int ni = 0; ni < 2; ni++)
          acc[mi][ni] = __builtin_amdgcn_mfma_f32_16x16x32_bf16(af[mi], bf2[ni], acc[mi][ni], 0, 0, 0);
    }
  }
}

// ---------------- FC1: h = gelu(xg @ w_fc^T + b_fc), bf16 out ---------------
// grid 3264 = 8 XCD-slots x 17 strips x 24 col-blocks (bid%8 -> XCD locality)
__global__ __launch_bounds__(512, 4) void fc1_kernel(
    const unsigned short* __restrict__ xg, const unsigned short* __restrict__ wfcb,
    const float* __restrict__ bfc, const int* __restrict__ po,
    unsigned short* __restrict__ h) {
  __shared__ char lds[65536];
  int bid = blockIdx.x;
  int r8 = bid & 7, g8 = bid >> 3;     // g8: 0..407
  int col = g8 % 24;
  int Sp  = g8 / 24;                   // 0..16
  int y   = r8 * 17 + Sp;              // 0..135
  int row0 = y * 128;
  if (row0 >= po[NEXP]) return;
  int e = 0;
#pragma unroll
  for (int i = 1; i < NEXP; i++) if (row0 >= po[i]) e = i;
  int n0 = col * 128;
  int tid = threadIdx.x;
  f32x4 acc[4][2];
#pragma unroll
  for (int mi = 0; mi < 4; mi++)
#pragma unroll
    for (int ni = 0; ni < 2; ni++) acc[mi][ni] = (f32x4){0.f, 0.f, 0.f, 0.f};
  gemm_core512(xg + (size_t)row0 * C_DIM, C_DIM,
               wfcb + (size_t)e * H_DIM * C_DIM + (size_t)n0 * C_DIM, C_DIM, C_DIM,
               lds, tid, acc);
  int w = tid >> 6, l = tid & 63;
  int wr = w >> 2, wc = w & 3, q = l >> 4;
  const float* bias = bfc + (size_t)e * H_DIM;
#pragma unroll
  for (int ni = 0; ni < 2; ni++) {
    int colw = n0 + wc * 32 + ni * 16 + (l & 15);
    float bv = bias[colw];
#pragma unroll
    for (int mi = 0; mi < 4; mi++) {
#pragma unroll
      for (int r = 0; r < 4; r++) {
        int row = row0 + wr * 64 + mi * 16 + q * 4 + r;
        float v = acc[mi][ni][r] + bv;
        float g = 0.5f * v * (1.0f + tanhf(0.7978845608028654f * (v + 0.044715f * v * v * v)));
        h[(size_t)row * H_DIM + colw] = f2b(g);
      }
    }
  }
}

// ---------------- FC2: part[z][pos] = w * (h_z @ w_proj^T + b_proj*[z==0]) --
// split-K=2 (K=1536 each), 1632 blocks, plain bf16 partial stores (no atomics)
__global__ __launch_bounds__(512, 4) void fc2_kernel(
    const unsigned short* __restrict__ h, const unsigned short* __restrict__ wpjb,
    const float* __restrict__ bproj, const int* __restrict__ po,
    const float* __restrict__ perm_w, unsigned short* __restrict__ part) {
  __shared__ char lds[65536];
  int bid = blockIdx.x;
  int r8 = bid & 7, g8 = bid >> 3;     // g8: 0..203
  int col = g8 % 6;
  int Sp  = g8 / 6;                    // 0..33
  int S   = r8 * 34 + Sp;              // 0..271 = z*136 + y
  int z   = S / 136;                   // k-split 0..1
  int y   = S - z * 136;
  int row0 = y * 128;
  if (row0 >= po[NEXP]) return;
  int e = 0;
#pragma unroll
  for (int i = 1; i < NEXP; i++) if (row0 >= po[i]) e = i;
  int n0 = col * 128;
  int koff = z * (H_DIM / 2);
  int tid = threadIdx.x;
  f32x4 acc[4][2];
#pragma unroll
  for (int mi = 0; mi < 4; mi++)
#pragma unroll
    for (int ni = 0; ni < 2; ni++) acc[mi][ni] = (f32x4){0.f, 0.f, 0.f, 0.f};
  gemm_core512(h + (size_t)row0 * H_DIM + koff, H_DIM,
               wpjb + (size_t)e * C_DIM * H_DIM + (size_t)n0 * H_DIM + koff, H_DIM, H_DIM / 2,
               lds, tid, acc);
  int w = tid >> 6, l = tid & 63;
  int wr = w >> 2, wc = w & 3, q = l >> 4;
  const float* bias = bproj + (size_t)e * C_DIM;
  unsigned short* pz = part + (size_t)z * PADCAP * C_DIM;
#pragma unroll
  for (int mi = 0; mi < 4; mi++) {
#pragma unroll
    for (int r = 0; r < 4; r++) {
      int pos = row0 + wr * 64 + mi * 16 + q * 4 + r;
      float wgt = perm_w[pos];   // 0 for pad rows -> stores 0, never read
#pragma unroll
      for (int ni = 0; ni < 2; ni++) {
        int colw = n0 + wc * 32 + ni * 16 + (l & 15);
        float v = acc[mi][ni][r];
        if (z == 0) v += bias[colw];        // bias exactly once across splits
        pz[(size_t)pos * C_DIM + colw] = f2b(v * wgt);
      }
    }
  }
}

// ---------------- combine: out[t] = sum of the token's 4 partial rows -------
__global__ __launch_bounds__(256) void combine_kernel(
    const unsigned short* __restrict__ part, const int* __restrict__ tok_pos,
    float* __restrict__ out) {
  const int NC4 = C_DIM / 4;                       // 192
  int idx = blockIdx.x * 256 + threadIdx.x;        // 0 .. N_TOK*192-1
  int t = idx / NC4, c4 = idx - t * NC4;
  int p0 = tok_pos[2 * t], p1 = tok_pos[2 * t + 1];
  const size_t SP = (size_t)PADCAP * C_DIM;
  const unsigned short* r00 = part + (size_t)p0 * C_DIM + c4 * 4;
  const unsigned short* r10 = part + (size_t)p1 * C_DIM + c4 * 4;
  ushort4 v00 = *(const ushort4*)r00;
  ushort4 v01 = *(const ushort4*)(r00 + SP);
  ushort4 v10 = *(const ushort4*)r10;
  ushort4 v11 = *(const ushort4*)(r10 + SP);
  float4 o;
  o.x = b2f(v00.x) + b2f(v01.x) + b2f(v10.x) + b2f(v11.x);
  o.y = b2f(v00.y) + b2f(v01.y) + b2f(v10.y) + b2f(v11.y);
  o.z = b2f(v00.z) + b2f(v01.z) + b2f(v10.z) + b2f(v11.z);
  o.w = b2f(v00.w) + b2f(v01.w) + b2f(v10.w) + b2f(v11.w);
  ((float4*)out)[idx] = o;
}

extern "C" void kernel_launch(void* const* d_in, const int* in_sizes, int n_in,
                              void* d_out, int out_size, void* d_ws, size_t ws_size,
                              hipStream_t stream) {
  const float* x     = (const float*)d_in[0];
  const float* gw    = (const float*)d_in[1];
  const float* gb    = (const float*)d_in[2];
  const float* wfc   = (const float*)d_in[3];
  const float* bfc   = (const float*)d_in[4];
  const float* wproj = (const float*)d_in[5];
  const float* bproj = (const float*)d_in[6];
  float* out = (float*)d_out;
  char* ws = (char*)d_ws;

  // ws layout (~209.6 MB total; part overlays xg+wfcb which die after FC1)
  int*   counts  = (int*)(ws + 0);
  int*   po      = (int*)(ws + 64);
  int*   tok_e   = (int*)(ws + 256);
  int*   tok_r   = (int*)(ws + 65792);
  float* tok_w   = (float*)(ws + 131328);
  int*   tok_pos = (int*)(ws + 196864);
  int*   perm_t  = (int*)(ws + 262400);
  float* perm_w  = (float*)(ws + 332032);
  const size_t ROUT_END = 401920;
  unsigned short* wpjb = (unsigned short*)(ws + 401920);        // 8x768x3072 bf16 -> ends 38,150,656
  unsigned short* hbuf = (unsigned short*)(ws + 38150656);      // 17408x3072 bf16 -> ends 145,105,408
  unsigned short* xg   = (unsigned short*)(ws + 145105408);     // 17408x768 bf16  -> ends 171,844,096
  unsigned short* wfcb = (unsigned short*)(ws + 171844096);     // 8x3072x768 bf16 -> ends 209,592,832
  unsigned short* part = (unsigned short*)(ws + 145105408);     // 2x17408x768 bf16 (overlay, ends 198,582,784)

  hipMemsetAsync(ws, 0, ROUT_END, stream);

  gate_kernel<<<N_TOK / 64, 256, 0, stream>>>(x, gw, gb, counts, tok_e, tok_r, tok_w);
  offsets_kernel<<<1, 64, 0, stream>>>(counts, po);
  scatter_kernel<<<N_TOK / 256, 256, 0, stream>>>(tok_e, tok_r, tok_w, po, perm_t, perm_w, tok_pos);
  gather_kernel<<<PADCAP / 4, 256, 0, stream>>>(x, po, perm_t, xg);
  wconv_kernel<<<2048, 256, 0, stream>>>(wfc, wproj, wfcb, wpjb);
  fc1_kernel<<<8 * 17 * 24, 512, 0, stream>>>(xg, wfcb, bfc, po, hbuf);
  fc2_kernel<<<8 * 34 * 6, 512, 0, stream>>>(hbuf, wpjb, bproj, po, perm_w, part);
  combine_kernel<<<N_TOK * (C_DIM / 4) / 256, 256, 0, stream>>>(part, tok_pos, out);
}